// Round 4
// baseline (914.118 us; speedup 1.0000x reference)
//
#include <hip/hip_runtime.h>

// ToDenseBEVConvolution R4 — phase-split design:
//  K1 bev_sort:    bucket point indices by k-bin.
//  K2 bev_point:   block = (k, 32-point chunk); kern[k] staged in LDS once;
//                  wave computes 8 same-k points -> f[N,128]; builds cell->point
//                  linked list (head/nxt) + compacted occupied-cell list.
//  K3 bev_zero:    pure streaming float4 zero-fill of out (268 MB @ ~6.2 TB/s).
//  K4 bev_scatter: one wave per occupied cell; wave-uniform list walk sums all
//                  colliding points' f rows (coalesced 512B reads), then 128
//                  plain scattered 4B stores (2/lane). No atomics on out, no
//                  divergence, one dependent-load level.

#define CIN    64
#define COUT   128
#define BEVH   512
#define BEVW   512
#define HW     (BEVH * BEVW)     // 2^18
#define NBINS  16
#define PTS_PER_WAVE  8
#define PTS_PER_BLOCK 32

// ---------------------------------------------------------------- K1: bucket
__global__ __launch_bounds__(256) void bev_sort(
    const int* __restrict__ coords,   // [N,4]
    const int* __restrict__ stride_p,
    int*       __restrict__ gcnt,     // [16] init 0
    int*       __restrict__ sorted,   // [16*N]
    int n)
{
    __shared__ int hist[NBINS];
    __shared__ int base[NBINS];
    const int tid = threadIdx.x;
    if (tid < NBINS) hist[tid] = 0;
    __syncthreads();

    const int i = blockIdx.x * 256 + tid;
    int k = 0, rank = 0;
    if (i < n) {
        k = coords[i * 4 + 1] / stride_p[0];
        rank = atomicAdd(&hist[k], 1);        // LDS atomic: block-local rank
    }
    __syncthreads();
    if (tid < NBINS)
        base[tid] = hist[tid] ? atomicAdd(&gcnt[tid], hist[tid]) : 0;
    __syncthreads();
    if (i < n)
        sorted[k * n + base[k] + rank] = i;
}

// ------------------------------------------------------- K2: per-point matmul
__global__ __launch_bounds__(256) void bev_point(
    const int*   __restrict__ coords,
    const float* __restrict__ feats,    // [N,64]
    const float* __restrict__ kern,     // [16,64,128]
    const int*   __restrict__ stride_p,
    const int*   __restrict__ gcnt,     // [16]
    const int*   __restrict__ sorted,   // [16*N]
    float*       __restrict__ f,        // [N,128]
    int*         __restrict__ head,     // [ncells] init -1
    int*         __restrict__ nxt,      // [N]
    int*         __restrict__ celllist, // [N] compacted occupied cells
    int*         __restrict__ ccount,   // [1] init 0
    int n, int chunks_per_bin)
{
    __shared__ float lk[CIN * COUT];    // 32 KB: kern[bin]

    const int bin   = blockIdx.x / chunks_per_bin;
    const int chunk = blockIdx.x % chunks_per_bin;
    const int cnt   = gcnt[bin];
    const int r0blk = chunk * PTS_PER_BLOCK;
    if (r0blk >= cnt) return;                 // uniform across block, pre-barrier: ok

    // stage kern[bin] -> LDS (256 thr x 8 float4)
    {
        const float4* src = (const float4*)(kern + (size_t)bin * CIN * COUT);
        float4* dst = (float4*)lk;
#pragma unroll
        for (int j = 0; j < 8; ++j)
            dst[j * 256 + threadIdx.x] = src[j * 256 + threadIdx.x];
    }
    __syncthreads();

    const int wave = threadIdx.x >> 6;
    const int lane = threadIdx.x & 63;
    const int r0 = r0blk + wave * PTS_PER_WAVE;
    const int navail = cnt - r0;
    if (navail <= 0) return;                  // no barrier after this point
    const int np = navail < PTS_PER_WAVE ? navail : PTS_PER_WAVE;

    int pts[PTS_PER_WAVE];
#pragma unroll
    for (int p = 0; p < PTS_PER_WAVE; ++p) {
        const int rr = (p < np) ? (r0 + p) : r0;   // pad tail with p0 (discarded)
        pts[p] = __builtin_amdgcn_readfirstlane(sorted[bin * n + rr]);
    }

    float ax[PTS_PER_WAVE], ay[PTS_PER_WAVE];
#pragma unroll
    for (int p = 0; p < PTS_PER_WAVE; ++p) { ax[p] = 0.f; ay[p] = 0.f; }

#pragma unroll
    for (int c = 0; c < CIN; ++c) {
        const float2 kv = *(const float2*)&lk[c * COUT + 2 * lane];
#pragma unroll
        for (int p = 0; p < PTS_PER_WAVE; ++p) {
            const float fv = feats[(size_t)pts[p] * CIN + c];  // wave-uniform -> s_load
            ax[p] = fmaf(fv, kv.x, ax[p]);
            ay[p] = fmaf(fv, kv.y, ay[p]);
        }
    }

#pragma unroll
    for (int p = 0; p < PTS_PER_WAVE; ++p) {
        if (p < np)
            *(float2*)(f + (size_t)pts[p] * COUT + 2 * lane) = make_float2(ax[p], ay[p]);
    }

    if (lane == 0) {
        const int stride = stride_p[0];
        for (int p = 0; p < np; ++p) {
            const int pt = pts[p];
            const int cx = coords[pt * 4 + 0];
            const int cz = coords[pt * 4 + 2];
            const int cb = coords[pt * 4 + 3];
            const int cell = (cb << 18) + ((cx / stride) << 9) + (cz / stride);
            const int old = atomicExch(&head[cell], pt);
            nxt[pt] = old;
            if (old < 0) {                    // first point in this cell: publish it
                const int t = atomicAdd(ccount, 1);
                celllist[t] = cell;
            }
        }
    }
}

// -------------------------------------------------------- K3: pure zero fill
__global__ __launch_bounds__(256) void bev_zero(
    float4* __restrict__ out4, int total4)   // total4 = out_size/4
{
    const int idx = blockIdx.x * 256 + threadIdx.x;
    const int quarter = total4 >> 2;
    const float4 z = make_float4(0.f, 0.f, 0.f, 0.f);
#pragma unroll
    for (int r = 0; r < 4; ++r)              // 4 coalesced sweeps
        out4[idx + r * quarter] = z;
}

// -------------------------------------------------- K4: per-cell plain scatter
__global__ __launch_bounds__(256) void bev_scatter(
    const float* __restrict__ f,        // [N,128]
    const int*   __restrict__ head,
    const int*   __restrict__ nxt,
    const int*   __restrict__ celllist,
    const int*   __restrict__ ccount,
    float*       __restrict__ out)      // [B,128,512,512]
{
    const int wave = threadIdx.x >> 6;
    const int lane = threadIdx.x & 63;
    const int w = blockIdx.x * 4 + wave;
    if (w >= *ccount) return;

    const int cell = __builtin_amdgcn_readfirstlane(celllist[w]);
    const int b = cell >> 18;
    const int x = (cell >> 9) & 511;
    const int z = cell & 511;

    int p = __builtin_amdgcn_readfirstlane(head[cell]);
    float sx = 0.f, sy = 0.f;
    while (p >= 0) {                          // wave-uniform walk, avg length ~1.04
        const float2 v = *(const float2*)(f + (size_t)p * COUT + 2 * lane);
        sx += v.x; sy += v.y;
        p = __builtin_amdgcn_readfirstlane(nxt[p]);
    }

    const size_t base = ((size_t)b * COUT + 2 * lane) * HW + (x << 9) + z;
    out[base]      = sx;                      // plain stores: cell owned by this wave
    out[base + HW] = sy;
}

// ------------------------------------------------------------------- launch
extern "C" void kernel_launch(void* const* d_in, const int* in_sizes, int n_in,
                              void* d_out, int out_size, void* d_ws, size_t ws_size,
                              hipStream_t stream) {
    const int*   coords   = (const int*)d_in[0];
    const float* feats    = (const float*)d_in[1];
    const float* kern     = (const float*)d_in[2];
    const int*   stride_p = (const int*)d_in[3];
    float* out = (float*)d_out;

    const int n      = in_sizes[0] / 4;      // coords is [N,4]
    const int ncells = out_size / COUT;      // B*H*W = 524288

    // Workspace layout: f | head | nxt | sorted | celllist | gcnt+ccount
    size_t off = 0;
    float* f = (float*)((char*)d_ws + off);          off += (size_t)n * COUT * sizeof(float);
    int* head = (int*)((char*)d_ws + off);           off += (size_t)ncells * sizeof(int);
    int* nxt  = (int*)((char*)d_ws + off);           off += (size_t)n * sizeof(int);
    int* sorted = (int*)((char*)d_ws + off);         off += (size_t)NBINS * n * sizeof(int);
    int* celllist = (int*)((char*)d_ws + off);       off += (size_t)n * sizeof(int);
    int* gcnt = (int*)((char*)d_ws + off);           off += NBINS * sizeof(int);
    int* ccount = (int*)((char*)d_ws + off);         off += sizeof(int);

    // ws is re-poisoned to 0xAA before every timed launch -> re-init.
    hipMemsetAsync(head, 0xFF, (size_t)ncells * sizeof(int), stream);   // -1
    hipMemsetAsync(gcnt, 0, (NBINS + 1) * sizeof(int), stream);         // gcnt + ccount

    bev_sort<<<(n + 255) / 256, 256, 0, stream>>>(coords, stride_p, gcnt, sorted, n);

    const int chunks_per_bin = (n + PTS_PER_BLOCK - 1) / PTS_PER_BLOCK;
    bev_point<<<NBINS * chunks_per_bin, 256, 0, stream>>>(
        coords, feats, kern, stride_p, gcnt, sorted, f, head, nxt,
        celllist, ccount, n, chunks_per_bin);

    const int total4 = out_size / 4;         // 16,777,216 float4s
    bev_zero<<<total4 / 4 / 256, 256, 0, stream>>>((float4*)out, total4);

    bev_scatter<<<(n + 3) / 4, 256, 0, stream>>>(f, head, nxt, celllist, ccount, out);
}

// Round 5
// 457.754 us; speedup vs baseline: 1.9970x; 1.9970x over previous
//
#include <hip/hip_runtime.h>

// ToDenseBEVConvolution R5:
//  K1 bev_sort:    bucket point indices by k-bin (LDS hist + global base).
//  K2 bev_point:   block = (k, 32-point chunk); kern[k] staged in LDS once;
//                  wave computes 8 same-k points -> f[N,128]; builds cell->point
//                  linked list (head via atomicExch, nxt). NO compaction counter
//                  (R4 lesson: 38.5k same-address atomicAdds = 461us stall).
//  memset(out):    rocclr fill @ ~6.2 TB/s (proven 43us for 268 MB).
//  K3 bev_scatter: one wave per POINT; wave owns its cell iff head[cell]==pt
//                  (exactly one owner per occupied cell). Owner walks the list
//                  (avg len 1.04), sums f rows (coalesced 512B reads), then 128
//                  plain scattered 4B stores. No atomics on out, no counter.

#define CIN    64
#define COUT   128
#define BEVH   512
#define BEVW   512
#define HW     (BEVH * BEVW)     // 2^18
#define NBINS  16
#define PTS_PER_WAVE  8
#define PTS_PER_BLOCK 32

// ---------------------------------------------------------------- K1: bucket
__global__ __launch_bounds__(256) void bev_sort(
    const int* __restrict__ coords,   // [N,4]
    const int* __restrict__ stride_p,
    int*       __restrict__ gcnt,     // [16] init 0
    int*       __restrict__ sorted,   // [16*N]
    int n)
{
    __shared__ int hist[NBINS];
    __shared__ int base[NBINS];
    const int tid = threadIdx.x;
    if (tid < NBINS) hist[tid] = 0;
    __syncthreads();

    const int i = blockIdx.x * 256 + tid;
    int k = 0, rank = 0;
    if (i < n) {
        k = coords[i * 4 + 1] / stride_p[0];
        rank = atomicAdd(&hist[k], 1);        // LDS atomic: block-local rank
    }
    __syncthreads();
    if (tid < NBINS)
        base[tid] = hist[tid] ? atomicAdd(&gcnt[tid], hist[tid]) : 0;
    __syncthreads();
    if (i < n)
        sorted[k * n + base[k] + rank] = i;
}

// ------------------------------------------------------- K2: per-point matmul
__global__ __launch_bounds__(256) void bev_point(
    const int*   __restrict__ coords,
    const float* __restrict__ feats,    // [N,64]
    const float* __restrict__ kern,     // [16,64,128]
    const int*   __restrict__ stride_p,
    const int*   __restrict__ gcnt,     // [16]
    const int*   __restrict__ sorted,   // [16*N]
    float*       __restrict__ f,        // [N,128]
    int*         __restrict__ head,     // [ncells] init -1
    int*         __restrict__ nxt,      // [N]
    int n, int chunks_per_bin)
{
    __shared__ float lk[CIN * COUT];    // 32 KB: kern[bin]

    const int bin   = blockIdx.x / chunks_per_bin;
    const int chunk = blockIdx.x % chunks_per_bin;
    const int cnt   = gcnt[bin];
    const int r0blk = chunk * PTS_PER_BLOCK;
    if (r0blk >= cnt) return;                 // uniform across block, pre-barrier: ok

    // stage kern[bin] -> LDS (256 thr x 8 float4)
    {
        const float4* src = (const float4*)(kern + (size_t)bin * CIN * COUT);
        float4* dst = (float4*)lk;
#pragma unroll
        for (int j = 0; j < 8; ++j)
            dst[j * 256 + threadIdx.x] = src[j * 256 + threadIdx.x];
    }
    __syncthreads();

    const int wave = threadIdx.x >> 6;
    const int lane = threadIdx.x & 63;
    const int r0 = r0blk + wave * PTS_PER_WAVE;
    const int navail = cnt - r0;
    if (navail <= 0) return;                  // no barrier after this point
    const int np = navail < PTS_PER_WAVE ? navail : PTS_PER_WAVE;

    int pts[PTS_PER_WAVE];
#pragma unroll
    for (int p = 0; p < PTS_PER_WAVE; ++p) {
        const int rr = (p < np) ? (r0 + p) : r0;   // pad tail with p0 (discarded)
        pts[p] = __builtin_amdgcn_readfirstlane(sorted[bin * n + rr]);
    }

    float ax[PTS_PER_WAVE], ay[PTS_PER_WAVE];
#pragma unroll
    for (int p = 0; p < PTS_PER_WAVE; ++p) { ax[p] = 0.f; ay[p] = 0.f; }

#pragma unroll
    for (int c = 0; c < CIN; ++c) {
        const float2 kv = *(const float2*)&lk[c * COUT + 2 * lane];
#pragma unroll
        for (int p = 0; p < PTS_PER_WAVE; ++p) {
            const float fv = feats[(size_t)pts[p] * CIN + c];  // wave-uniform -> s_load
            ax[p] = fmaf(fv, kv.x, ax[p]);
            ay[p] = fmaf(fv, kv.y, ay[p]);
        }
    }

#pragma unroll
    for (int p = 0; p < PTS_PER_WAVE; ++p) {
        if (p < np)
            *(float2*)(f + (size_t)pts[p] * COUT + 2 * lane) = make_float2(ax[p], ay[p]);
    }

    if (lane == 0) {
        const int stride = stride_p[0];
        for (int p = 0; p < np; ++p) {
            const int pt = pts[p];
            const int cx = coords[pt * 4 + 0];
            const int cz = coords[pt * 4 + 2];
            const int cb = coords[pt * 4 + 3];
            const int cell = (cb << 18) + ((cx / stride) << 9) + (cz / stride);
            const int old = atomicExch(&head[cell], pt);   // spread atomics: cheap
            nxt[pt] = old;
        }
    }
}

// -------------------------------------- K3: per-point scatter, head-ownership
__global__ __launch_bounds__(256) void bev_scatter(
    const int*   __restrict__ coords,
    const int*   __restrict__ stride_p,
    const float* __restrict__ f,        // [N,128]
    const int*   __restrict__ head,
    const int*   __restrict__ nxt,
    float*       __restrict__ out,      // [B,128,512,512]
    int n)
{
    const int wave = threadIdx.x >> 6;
    const int lane = threadIdx.x & 63;
    int pt = blockIdx.x * 4 + wave;
    if (pt >= n) return;
    pt = __builtin_amdgcn_readfirstlane(pt);    // wave-uniform -> scalar loads

    const int stride = stride_p[0];
    const int cx = coords[pt * 4 + 0];
    const int cz = coords[pt * 4 + 2];
    const int cb = coords[pt * 4 + 3];
    const int cell = (cb << 18) + ((cx / stride) << 9) + (cz / stride);

    // exactly one point per occupied cell is the list head: that wave owns it
    if (__builtin_amdgcn_readfirstlane(head[cell]) != pt) return;

    float sx = 0.f, sy = 0.f;
    int p = pt;
    while (p >= 0) {                            // wave-uniform walk, avg len ~1.04
        const float2 v = *(const float2*)(f + (size_t)p * COUT + 2 * lane);
        sx += v.x; sy += v.y;
        p = __builtin_amdgcn_readfirstlane(nxt[p]);
    }

    const int b = cell >> 18;
    const int xz = cell & (HW - 1);
    const size_t base = ((size_t)b * COUT + 2 * lane) * HW + xz;
    out[base]      = sx;                        // plain stores: wave owns the cell
    out[base + HW] = sy;
}

// ------------------------------------------------------------------- launch
extern "C" void kernel_launch(void* const* d_in, const int* in_sizes, int n_in,
                              void* d_out, int out_size, void* d_ws, size_t ws_size,
                              hipStream_t stream) {
    const int*   coords   = (const int*)d_in[0];
    const float* feats    = (const float*)d_in[1];
    const float* kern     = (const float*)d_in[2];
    const int*   stride_p = (const int*)d_in[3];
    float* out = (float*)d_out;

    const int n      = in_sizes[0] / 4;      // coords is [N,4]
    const int ncells = out_size / COUT;      // B*H*W = 524288

    // Workspace layout: f | head | nxt | sorted | gcnt
    size_t off = 0;
    float* f = (float*)((char*)d_ws + off);          off += (size_t)n * COUT * sizeof(float);
    int* head = (int*)((char*)d_ws + off);           off += (size_t)ncells * sizeof(int);
    int* nxt  = (int*)((char*)d_ws + off);           off += (size_t)n * sizeof(int);
    int* sorted = (int*)((char*)d_ws + off);         off += (size_t)NBINS * n * sizeof(int);
    int* gcnt = (int*)((char*)d_ws + off);           off += NBINS * sizeof(int);

    // ws is re-poisoned to 0xAA before every timed launch -> re-init.
    hipMemsetAsync(head, 0xFF, (size_t)ncells * sizeof(int), stream);   // -1
    hipMemsetAsync(gcnt, 0, NBINS * sizeof(int), stream);
    hipMemsetAsync(out, 0, (size_t)out_size * sizeof(float), stream);   // rocclr fill ~6.2 TB/s

    bev_sort<<<(n + 255) / 256, 256, 0, stream>>>(coords, stride_p, gcnt, sorted, n);

    const int chunks_per_bin = (n + PTS_PER_BLOCK - 1) / PTS_PER_BLOCK;
    bev_point<<<NBINS * chunks_per_bin, 256, 0, stream>>>(
        coords, feats, kern, stride_p, gcnt, sorted, f, head, nxt, n, chunks_per_bin);

    bev_scatter<<<(n + 3) / 4, 256, 0, stream>>>(coords, stride_p, f, head, nxt, out, n);
}

// Round 7
// 388.076 us; speedup vs baseline: 2.3555x; 1.1795x over previous
//
#include <hip/hip_runtime.h>

// ToDenseBEVConvolution R6b — rank-compaction + fused single-pass output:
//  K1 bev_sort:  bucket point indices by k-bin (LDS hist + global base).
//  K2 bev_point: block = (k, 32-pt chunk); kern[k] in LDS once; wave computes 8
//                same-k points -> f[N,128]; builds head/nxt lists (spread
//                atomicExch) + bm occupancy bitmask (spread atomicOr).
//  K3 bev_scan:  single block; wordbase[w] = exclusive prefix of popc(bm[w]).
//  K4 bev_accum: wave per point; owner (head[cell]==pt) sums collision list,
//                writes compacted g[rank][128] (coalesced 512B, L2/L3-resident).
//  K5 bev_dense: one float4/thread in output-linear order; rank via
//                wordbase+popc (no pointer chase); empty nibble -> zeros.
//                Writes out EXACTLY ONCE, streaming, nontemporal (native vec4
//                type — HIP_vector_type rejected by the builtin). No memset of
//                out, no write-allocate RMW (R5 lesson: scattered 4B stores into
//                evicted 268MB = ~320MB random RMW traffic @ 1.2 TB/s).

#define CIN    64
#define COUT   128
#define BEVH   512
#define BEVW   512
#define HW     (BEVH * BEVW)     // 2^18
#define NBINS  16
#define PTS_PER_WAVE  8
#define PTS_PER_BLOCK 32

typedef float nvec4 __attribute__((ext_vector_type(4)));   // native vec for nt-store

// ---------------------------------------------------------------- K1: bucket
__global__ __launch_bounds__(256) void bev_sort(
    const int* __restrict__ coords,   // [N,4]
    const int* __restrict__ stride_p,
    int*       __restrict__ gcnt,     // [16] init 0
    int*       __restrict__ sorted,   // [16*N]
    int n)
{
    __shared__ int hist[NBINS];
    __shared__ int base[NBINS];
    const int tid = threadIdx.x;
    if (tid < NBINS) hist[tid] = 0;
    __syncthreads();

    const int i = blockIdx.x * 256 + tid;
    int k = 0, rank = 0;
    if (i < n) {
        k = coords[i * 4 + 1] / stride_p[0];
        rank = atomicAdd(&hist[k], 1);        // LDS atomic: block-local rank
    }
    __syncthreads();
    if (tid < NBINS)
        base[tid] = hist[tid] ? atomicAdd(&gcnt[tid], hist[tid]) : 0;
    __syncthreads();
    if (i < n)
        sorted[k * n + base[k] + rank] = i;
}

// ------------------------------------------------------- K2: per-point matmul
__global__ __launch_bounds__(256) void bev_point(
    const int*   __restrict__ coords,
    const float* __restrict__ feats,    // [N,64]
    const float* __restrict__ kern,     // [16,64,128]
    const int*   __restrict__ stride_p,
    const int*   __restrict__ gcnt,     // [16]
    const int*   __restrict__ sorted,   // [16*N]
    float*       __restrict__ f,        // [N,128]
    int*         __restrict__ head,     // [ncells] init -1
    int*         __restrict__ nxt,      // [N]
    unsigned int* __restrict__ bm,      // [ncells/32] init 0
    int n, int chunks_per_bin)
{
    __shared__ float lk[CIN * COUT];    // 32 KB: kern[bin]

    const int bin   = blockIdx.x / chunks_per_bin;
    const int chunk = blockIdx.x % chunks_per_bin;
    const int cnt   = gcnt[bin];
    const int r0blk = chunk * PTS_PER_BLOCK;
    if (r0blk >= cnt) return;                 // uniform across block, pre-barrier: ok

    // stage kern[bin] -> LDS (256 thr x 8 float4)
    {
        const float4* src = (const float4*)(kern + (size_t)bin * CIN * COUT);
        float4* dst = (float4*)lk;
#pragma unroll
        for (int j = 0; j < 8; ++j)
            dst[j * 256 + threadIdx.x] = src[j * 256 + threadIdx.x];
    }
    __syncthreads();

    const int wave = threadIdx.x >> 6;
    const int lane = threadIdx.x & 63;
    const int r0 = r0blk + wave * PTS_PER_WAVE;
    const int navail = cnt - r0;
    if (navail <= 0) return;                  // no barrier after this point
    const int np = navail < PTS_PER_WAVE ? navail : PTS_PER_WAVE;

    int pts[PTS_PER_WAVE];
#pragma unroll
    for (int p = 0; p < PTS_PER_WAVE; ++p) {
        const int rr = (p < np) ? (r0 + p) : r0;   // pad tail with p0 (discarded)
        pts[p] = __builtin_amdgcn_readfirstlane(sorted[bin * n + rr]);
    }

    float ax[PTS_PER_WAVE], ay[PTS_PER_WAVE];
#pragma unroll
    for (int p = 0; p < PTS_PER_WAVE; ++p) { ax[p] = 0.f; ay[p] = 0.f; }

#pragma unroll
    for (int c = 0; c < CIN; ++c) {
        const float2 kv = *(const float2*)&lk[c * COUT + 2 * lane];
#pragma unroll
        for (int p = 0; p < PTS_PER_WAVE; ++p) {
            const float fv = feats[(size_t)pts[p] * CIN + c];  // wave-uniform -> s_load
            ax[p] = fmaf(fv, kv.x, ax[p]);
            ay[p] = fmaf(fv, kv.y, ay[p]);
        }
    }

#pragma unroll
    for (int p = 0; p < PTS_PER_WAVE; ++p) {
        if (p < np)
            *(float2*)(f + (size_t)pts[p] * COUT + 2 * lane) = make_float2(ax[p], ay[p]);
    }

    if (lane == 0) {
        const int stride = stride_p[0];
        for (int p = 0; p < np; ++p) {
            const int pt = pts[p];
            const int cx = coords[pt * 4 + 0];
            const int cz = coords[pt * 4 + 2];
            const int cb = coords[pt * 4 + 3];
            const int cell = (cb << 18) + ((cx / stride) << 9) + (cz / stride);
            const int old = atomicExch(&head[cell], pt);       // spread: cheap
            nxt[pt] = old;
            atomicOr(&bm[cell >> 5], 1u << (cell & 31));       // spread: cheap
        }
    }
}

// --------------------------------------- K3: word-level popcount prefix scan
__global__ __launch_bounds__(256) void bev_scan(
    const unsigned int* __restrict__ bm,        // [nwords]
    int*                __restrict__ wordbase,  // [nwords] exclusive prefix
    int nwords)
{
    __shared__ int part[256];
    const int tid = threadIdx.x;
    const int per = (nwords + 255) / 256;       // 64 for B=2
    const int w0  = tid * per;

    int s = 0;
    for (int i = 0; i < per; ++i) {
        const int w = w0 + i;
        if (w < nwords) s += __popc(bm[w]);
    }
    part[tid] = s;
    __syncthreads();
    for (int d = 1; d < 256; d <<= 1) {         // Hillis-Steele inclusive scan
        const int v = (tid >= d) ? part[tid - d] : 0;
        __syncthreads();
        part[tid] += v;
        __syncthreads();
    }
    int base = (tid == 0) ? 0 : part[tid - 1];  // exclusive
    for (int i = 0; i < per; ++i) {
        const int w = w0 + i;
        if (w < nwords) { wordbase[w] = base; base += __popc(bm[w]); }
    }
}

// ----------------------------- K4: owner combines collisions -> compacted g
__global__ __launch_bounds__(256) void bev_accum(
    const int*          __restrict__ coords,
    const int*          __restrict__ stride_p,
    const float*        __restrict__ f,         // [N,128]
    const int*          __restrict__ head,
    const int*          __restrict__ nxt,
    const unsigned int* __restrict__ bm,
    const int*          __restrict__ wordbase,
    float*              __restrict__ g,         // [nocc,128] compacted
    int n)
{
    const int wave = threadIdx.x >> 6;
    const int lane = threadIdx.x & 63;
    int pt = blockIdx.x * 4 + wave;
    if (pt >= n) return;
    pt = __builtin_amdgcn_readfirstlane(pt);

    const int stride = stride_p[0];
    const int cx = coords[pt * 4 + 0];
    const int cz = coords[pt * 4 + 2];
    const int cb = coords[pt * 4 + 3];
    const int cell = (cb << 18) + ((cx / stride) << 9) + (cz / stride);

    // exactly one point per occupied cell is the list head: that wave owns it
    if (__builtin_amdgcn_readfirstlane(head[cell]) != pt) return;

    float sx = 0.f, sy = 0.f;
    int p = pt;
    while (p >= 0) {                            // wave-uniform walk, avg len ~1.04
        const float2 v = *(const float2*)(f + (size_t)p * COUT + 2 * lane);
        sx += v.x; sy += v.y;
        p = __builtin_amdgcn_readfirstlane(nxt[p]);
    }

    const unsigned int word = bm[cell >> 5];
    const int bit = cell & 31;
    const int rank = wordbase[cell >> 5] + __popc(word & ((1u << bit) - 1u));

    *(float2*)(g + (size_t)rank * COUT + 2 * lane) = make_float2(sx, sy);  // 512B/cell
}

// ----------------------------------- K5: fused zero+gather, single write pass
__global__ __launch_bounds__(256) void bev_dense(
    const float*        __restrict__ g,         // [nocc,128]
    const unsigned int* __restrict__ bm,
    const int*          __restrict__ wordbase,
    float*              __restrict__ out,       // [B,128,512,512]
    int total4)
{
    const int t = blockIdx.x * 256 + threadIdx.x;
    if (t >= total4) return;
    const int linear = t << 2;                  // z%4==0 guaranteed
    const int z = linear & 511;
    const int x = (linear >> 9) & 511;
    const int o = (linear >> 18) & 127;
    const int b = linear >> 25;
    const int cell = (b << 18) + (x << 9) + z;  // bits bit..bit+3 in one bm word

    const unsigned int word = bm[cell >> 5];
    const int bit = cell & 31;
    const unsigned int nib = (word >> bit) & 0xFu;

    nvec4 v = {0.f, 0.f, 0.f, 0.f};
    if (nib) {
        int r = wordbase[cell >> 5] + __popc(word & ((1u << bit) - 1u));
#pragma unroll
        for (int j = 0; j < 4; ++j) {
            if (nib & (1u << j)) { v[j] = g[(size_t)r * COUT + o]; ++r; }
        }
    }
    __builtin_nontemporal_store(v, (nvec4*)(out + linear));  // don't evict g
}

// ------------------------------------------------------------------- launch
extern "C" void kernel_launch(void* const* d_in, const int* in_sizes, int n_in,
                              void* d_out, int out_size, void* d_ws, size_t ws_size,
                              hipStream_t stream) {
    const int*   coords   = (const int*)d_in[0];
    const float* feats    = (const float*)d_in[1];
    const float* kern     = (const float*)d_in[2];
    const int*   stride_p = (const int*)d_in[3];
    float* out = (float*)d_out;

    const int n      = in_sizes[0] / 4;      // coords is [N,4]
    const int ncells = out_size / COUT;      // B*H*W = 524288
    const int nwords = ncells / 32;          // 16384

    // Workspace: f | g | sorted | head | nxt | wordbase | bm | gcnt
    size_t off = 0;
    float* f = (float*)((char*)d_ws + off);          off += (size_t)n * COUT * sizeof(float);
    float* g = (float*)((char*)d_ws + off);          off += (size_t)n * COUT * sizeof(float);
    int* sorted = (int*)((char*)d_ws + off);         off += (size_t)NBINS * n * sizeof(int);
    int* head = (int*)((char*)d_ws + off);           off += (size_t)ncells * sizeof(int);
    int* nxt  = (int*)((char*)d_ws + off);           off += (size_t)n * sizeof(int);
    int* wordbase = (int*)((char*)d_ws + off);       off += (size_t)nwords * sizeof(int);
    unsigned int* bm = (unsigned int*)((char*)d_ws + off); off += (size_t)nwords * sizeof(unsigned int);
    int* gcnt = (int*)((char*)d_ws + off);           off += NBINS * sizeof(int);

    // ws re-poisoned to 0xAA before every timed launch -> re-init.
    (void)hipMemsetAsync(head, 0xFF, (size_t)ncells * sizeof(int), stream);     // -1
    (void)hipMemsetAsync(bm, 0,
                         (size_t)nwords * sizeof(unsigned int) + NBINS * sizeof(int),
                         stream);                                               // bm + gcnt

    bev_sort<<<(n + 255) / 256, 256, 0, stream>>>(coords, stride_p, gcnt, sorted, n);

    const int chunks_per_bin = (n + PTS_PER_BLOCK - 1) / PTS_PER_BLOCK;
    bev_point<<<NBINS * chunks_per_bin, 256, 0, stream>>>(
        coords, feats, kern, stride_p, gcnt, sorted, f, head, nxt, bm,
        n, chunks_per_bin);

    bev_scan<<<1, 256, 0, stream>>>(bm, wordbase, nwords);

    bev_accum<<<(n + 3) / 4, 256, 0, stream>>>(coords, stride_p, f, head, nxt,
                                               bm, wordbase, g, n);

    const int total4 = out_size / 4;
    bev_dense<<<(total4 + 255) / 256, 256, 0, stream>>>(g, bm, wordbase, out, total4);
}